// Round 10
// baseline (127.436 us; speedup 1.0000x reference)
//
#include <hip/hip_runtime.h>
#include <hip/hip_fp16.h>

#define BB 4
#define AA 512
#define ZS 8          // angle slices (one per XCD)
#define AH (AA / ZS)  // 64 angles per slice
#define DD 729
#define HH 512
#define WW 512
#define CH 4          // angles per chunk
#define NC (AH / CH)  // 16 chunks
#define WIN 64        // window bins per angle (R30: widened for 32-tall tile)
#define AD (AA * DD)  // batch stride (elements)
#define GX (WW / 64)  // 8 blocks in x (64 px wide: 4 waves x 16)
#define GY (HH / 32)  // 16 blocks in y (wave tile 32 tall)

typedef float        f4v  __attribute__((ext_vector_type(4)));
typedef unsigned int u4v8 __attribute__((ext_vector_type(4), aligned(8)));
typedef unsigned int u2v8 __attribute__((ext_vector_type(2), aligned(8)));

__device__ inline float buf_load1(__amdgpu_buffer_rsrc_t r, int elem) {
    union { unsigned int u; float f; } c;
    c.u = __builtin_amdgcn_raw_buffer_load_b32(r, elem * 4, 0, 0);
    return c.f;
}
__device__ inline __half2 h2bc(unsigned int x) {
    return __builtin_bit_cast(__half2, x);
}
__device__ inline unsigned int pk2u(float a, float b) {
    return __builtin_bit_cast(unsigned int, __builtin_amdgcn_cvt_pkrtz(a, b));
}

// R30: amortize per-chunk DS overhead over 2x pixels. R29 closed the
// model: DS pipe is per-CU and SATURATED -- 288 cyc/chunk/wave (16 tap
// reads 192 + broadcasts 72 + writes 24) x 16 chunks x 32 waves/CU =
// 61.4us vs 62.0 measured. All nine nulls explained: they rearranged DS
// cycles without reducing them. The overhead term (96 cyc) is per-WAVE
// while tap reads are per-PIXEL, so R30 gives each wave a 16x32 tile
// (8 y-rows/lane): WIN 32->64 (dev 7.5|c|+15.5|s| <= 17.3; s0 =
// trunc(uc)-32 clamped [0, DD-64] -> li in [0.6, 61.3], checked at both
// clamp edges). Staging: lane l owns bin l, loads 4 batches (coalesced
// b32 x4), 2 pkrtz, ONE b64 write to slots {2l,2l+1}. Slot layout
// (j*WIN+e)*2+h is form-identical to R25 -> LERP body and its 8B-
// aligned contiguous read unchanged; per-pixel math bit-identical.
// Per chunk: 32 taps (384) + bcast 72 + writes 24 = 480 cyc / 512 px
// = 0.94 DS cyc/px vs 1.125 (-17%). VALU ~40%/SIMD (slack). Fences
// kept (R26). Grid 1024 blocks, 16 waves/CU (= observed effective
// residency all session).
__global__ __launch_bounds__(256, 4) void bp_kernel(
    const float* __restrict__ sino,
    const float* __restrict__ vol_origin,
    const float* __restrict__ det_origin,
    const float* __restrict__ vol_spacing,
    const float* __restrict__ det_spacing,
    const float* __restrict__ angles,
    float* __restrict__ out)
{
    __shared__ f4v          s_csk[4][AH];           // per-wave consts
    __shared__ int          s_s0[4][AH];            // per-wave window starts
    __shared__ __align__(16) unsigned int s_win[4][CH * WIN * 2]; // f16 windows

    const int tid  = threadIdx.y * 16 + threadIdx.x;   // block 16x16 = 4 waves
    const int lane = tid & 63;
    const int wv   = tid >> 6;                          // wave id = tile id

    // XCD-slice swizzle: linear dispatch id (x fastest), XCD = n % ZS.
    const int nlin = (int)blockIdx.x + GX * ((int)blockIdx.y + GY * (int)blockIdx.z);
    const int zsl  = nlin & (ZS - 1);      // slice == XCD
    const int mm   = nlin >> 3;            // 0..GX*GY-1 within slice
    const int bxx  = mm & (GX - 1);
    const int byy  = mm >> 3;              // GX == 8

    const float inv_ds = 1.0f / det_spacing[0];
    const int abase = zsl * AH;

    const int x0 = bxx * 64 + wv * 16;   // this wave's tile: 16 x 32
    const int y0 = byy * 32;
    const float vsx = vol_spacing[1], vsy = vol_spacing[0];
    const float off = -det_origin[0] * inv_ds;
    // Tile 16x32 center; max tap deviation 7.5|c|+15.5|s| <= 17.3 bins.
    // s0 = trunc(uc)-32 clamped [0, DD-WIN]: unclamped li = (u-uc)+
    // frac(uc)+32 in [14.6, 50.4]; low clamp (uc<33): li = u in
    // (2.7, 50.4]; high clamp (uc>=698): li = u-665 in [15.6, 60.3].
    // All cases: li+1 <= 62 < WIN.
    const float xc = vol_origin[1] + ((float)x0 + 7.5f) * vsx;
    const float yc = vol_origin[0] + ((float)y0 + 15.5f) * vsy;

    {   // AH=64 entries, 64 lanes per wave: one each, into this wave's slot.
        const int a = lane;
        float th = angles[abase + a];
        float c = cosf(th) * inv_ds;
        float s = sinf(th) * inv_ds;
        float uc = fmaf(xc, c, fmaf(yc, s, off));
        int s0 = min(max((int)uc - (WIN / 2), 0), DD - WIN);
        f4v k;
        k.x = c; k.y = s; k.z = off - (float)s0; k.w = 4.0f * vsy * s;
        s_csk[wv][a] = k;
        s_s0[wv][a]  = s0;
    }
    __threadfence_block();   // intra-wave publish of csk/s0 (no s_barrier)

    // Pixels: column ix, rows iy0 + 4*r for r = 0..7.
    const int ix  = x0 + threadIdx.x;
    const int iy0 = y0 + (threadIdx.y & 3);
    const float xw = vol_origin[1] + (float)ix * vsx;
    const float yw = vol_origin[0] + (float)iy0 * vsy;

    const __amdgpu_buffer_rsrc_t rsrc = __builtin_amdgcn_make_buffer_rsrc(
        (void*)sino, (short)0, BB * AA * DD * 4, 0x00020000);

    f4v acc0 = {0.f,0.f,0.f,0.f}, acc1 = {0.f,0.f,0.f,0.f};
    f4v acc2 = {0.f,0.f,0.f,0.f}, acc3 = {0.f,0.f,0.f,0.f};
    f4v acc4 = {0.f,0.f,0.f,0.f}, acc5 = {0.f,0.f,0.f,0.f};
    f4v acc6 = {0.f,0.f,0.f,0.f}, acc7 = {0.f,0.f,0.f,0.f};

    const __half2 hz   = h2bc(0u);
    const __half2 one2 = h2bc(0x3C003C00u);   // (1.0h, 1.0h)
    __half2 h01_0 = hz, h23_0 = hz, h01_1 = hz, h23_1 = hz;
    __half2 h01_2 = hz, h23_2 = hz, h01_3 = hz, h23_3 = hz;
    __half2 h01_4 = hz, h23_4 = hz, h01_5 = hz, h23_5 = hz;
    __half2 h01_6 = hz, h23_6 = hz, h01_7 = hz, h23_7 = hz;

    // Staging regs: angle A..D (4 per chunk), batches 0..3. Lane l owns
    // bin l of each angle's window.
    float vA0, vA1, vA2, vA3, vB0, vB1, vB2, vB3;
    float vC0, vC1, vC2, vC3, vD0, vD1, vD2, vD3;

    #define STAGE_LOAD(C)                                                  \
        do {                                                               \
            const int aa = (C) * CH;                                       \
            const int r0 = (abase + aa + 0) * DD + s_s0[wv][aa + 0] + lane;\
            const int r1 = (abase + aa + 1) * DD + s_s0[wv][aa + 1] + lane;\
            const int r2 = (abase + aa + 2) * DD + s_s0[wv][aa + 2] + lane;\
            const int r3 = (abase + aa + 3) * DD + s_s0[wv][aa + 3] + lane;\
            vA0 = buf_load1(rsrc, r0);          vA1 = buf_load1(rsrc, r0 + AD);     \
            vA2 = buf_load1(rsrc, r0 + 2 * AD); vA3 = buf_load1(rsrc, r0 + 3 * AD); \
            vB0 = buf_load1(rsrc, r1);          vB1 = buf_load1(rsrc, r1 + AD);     \
            vB2 = buf_load1(rsrc, r1 + 2 * AD); vB3 = buf_load1(rsrc, r1 + 3 * AD); \
            vC0 = buf_load1(rsrc, r2);          vC1 = buf_load1(rsrc, r2 + AD);     \
            vC2 = buf_load1(rsrc, r2 + 2 * AD); vC3 = buf_load1(rsrc, r2 + 3 * AD); \
            vD0 = buf_load1(rsrc, r3);          vD1 = buf_load1(rsrc, r3 + AD);     \
            vD2 = buf_load1(rsrc, r3 + 2 * AD); vD3 = buf_load1(rsrc, r3 + 3 * AD); \
        } while (0)

    // Slot (j*WIN+e)*2 + h: h=0 -> (b0,b1)@e, h=1 -> (b2,b3)@e. Lane l
    // writes both h's of bin l as one b64 at u32 index j*128 + 2l.
    #define CONVERT_WRITE()                                                \
        do {                                                               \
            u2v8 q;                                                        \
            q.x = pk2u(vA0, vA1); q.y = pk2u(vA2, vA3);                    \
            *(u2v8*)&s_win[wv][0 * 128 + 2 * lane] = q;                    \
            q.x = pk2u(vB0, vB1); q.y = pk2u(vB2, vB3);                    \
            *(u2v8*)&s_win[wv][1 * 128 + 2 * lane] = q;                    \
            q.x = pk2u(vC0, vC1); q.y = pk2u(vC2, vC3);                    \
            *(u2v8*)&s_win[wv][2 * 128 + 2 * lane] = q;                    \
            q.x = pk2u(vD0, vD1); q.y = pk2u(vD2, vD3);                    \
            *(u2v8*)&s_win[wv][3 * 128 + 2 * lane] = q;                    \
        } while (0)

    // t.x=(b0,b1)@li, t.y=(b2,b3)@li, t.z=(b0,b1)@li+1, t.w=(b2,b3)@li+1.
    #define LERP(U, H01, H23)                                              \
        do {                                                               \
            const int   li = (int)(U);                                     \
            const float fr = __builtin_amdgcn_fractf(U);                   \
            const __half2 fr2 = h2bc(pk2u(fr, fr));                        \
            const __half2 om2 = __hsub2(one2, fr2);                        \
            const u4v8 t = *(const u4v8*)&s_win[wv][(j * WIN + li) * 2];   \
            H01 = __hfma2(h2bc(t.x), om2, __hfma2(h2bc(t.z), fr2, H01));   \
            H23 = __hfma2(h2bc(t.y), om2, __hfma2(h2bc(t.w), fr2, H23));   \
        } while (0)

    #define WIDEN(H01, H23, ACC)                                           \
        do {                                                               \
            (ACC).x += __low2float(H01);  (ACC).y += __high2float(H01);    \
            (ACC).z += __low2float(H23);  (ACC).w += __high2float(H23);    \
            H01 = hz; H23 = hz;                                            \
        } while (0)

    STAGE_LOAD(0);
    for (int c = 0; c < NC; ++c) {
        __threadfence_block();   // consume of previous chunk done (intra-wave)
        CONVERT_WRITE();         // publish chunk c (regs -> LDS)
        __threadfence_block();   // writes ordered before consume reads
        if (c + 1 < NC) STAGE_LOAD(c + 1);   // next chunk's loads fly now
        #pragma unroll
        for (int j = 0; j < CH; ++j) {
            const f4v k = s_csk[wv][c * CH + j];
            float u = fmaf(xw, k.x, fmaf(yw, k.y, k.z)); // u-s0 in [0.6, 61.3]
            LERP(u, h01_0, h23_0); u += k.w;
            LERP(u, h01_1, h23_1); u += k.w;
            LERP(u, h01_2, h23_2); u += k.w;
            LERP(u, h01_3, h23_3); u += k.w;
            LERP(u, h01_4, h23_4); u += k.w;
            LERP(u, h01_5, h23_5); u += k.w;
            LERP(u, h01_6, h23_6); u += k.w;
            LERP(u, h01_7, h23_7);
        }
        // widen f16 chunk-partials (8 terms each) into f32 accumulators
        WIDEN(h01_0, h23_0, acc0);
        WIDEN(h01_1, h23_1, acc1);
        WIDEN(h01_2, h23_2, acc2);
        WIDEN(h01_3, h23_3, acc3);
        WIDEN(h01_4, h23_4, acc4);
        WIDEN(h01_5, h23_5, acc5);
        WIDEN(h01_6, h23_6, acc6);
        WIDEN(h01_7, h23_7, acc7);
    }
    #undef STAGE_LOAD
    #undef CONVERT_WRITE
    #undef LERP
    #undef WIDEN

    const size_t HW = (size_t)HH * WW;
    #define OUT4(ACC, ROWOFF)                                              \
        do {                                                               \
            const size_t o = (size_t)(iy0 + (ROWOFF)) * WW + ix;           \
            unsafeAtomicAdd(&out[o],          (ACC).x);                    \
            unsafeAtomicAdd(&out[o + HW],     (ACC).y);                    \
            unsafeAtomicAdd(&out[o + 2 * HW], (ACC).z);                    \
            unsafeAtomicAdd(&out[o + 3 * HW], (ACC).w);                    \
        } while (0)
    OUT4(acc0, 0);
    OUT4(acc1, 4);
    OUT4(acc2, 8);
    OUT4(acc3, 12);
    OUT4(acc4, 16);
    OUT4(acc5, 20);
    OUT4(acc6, 24);
    OUT4(acc7, 28);
    #undef OUT4
}

extern "C" void kernel_launch(void* const* d_in, const int* in_sizes, int n_in,
                              void* d_out, int out_size, void* d_ws, size_t ws_size,
                              hipStream_t stream) {
    const float* sino        = (const float*)d_in[0];
    // d_in[1] = volume_shape (int64) — compile-time constants HH/WW used.
    const float* vol_origin  = (const float*)d_in[2];
    const float* det_origin  = (const float*)d_in[3];
    const float* vol_spacing = (const float*)d_in[4];
    const float* det_spacing = (const float*)d_in[5];
    const float* angles      = (const float*)d_in[6];
    float* out = (float*)d_out;

    // ZS grid-z slices accumulate atomically into a zeroed output.
    hipMemsetAsync(d_out, 0, (size_t)out_size * sizeof(float), stream);

    dim3 block(16, 16, 1);
    dim3 grid(GX, GY, ZS);
    bp_kernel<<<grid, block, 0, stream>>>(sino, vol_origin, det_origin,
                                          vol_spacing, det_spacing, angles, out);
}